// Round 4
// baseline (163.565 us; speedup 1.0000x reference)
//
#include <hip/hip_runtime.h>
#include <hip/hip_bf16.h>
#include <math.h>

#define SELU_SCALE 1.0507009873554805f
#define SELU_ALPHA 1.6732632423543772f

static constexpr int B_ = 16, T_ = 16, L_ = 512, H_ = 768;

typedef __bf16 bf16x8 __attribute__((ext_vector_type(8)));
typedef __bf16 bf16x4 __attribute__((ext_vector_type(4)));
typedef float  f32x4  __attribute__((ext_vector_type(4)));

__device__ __forceinline__ float bf_lo(unsigned u) { return __uint_as_float(u << 16); }
__device__ __forceinline__ float bf_hi(unsigned u) { return __uint_as_float(u & 0xFFFF0000u); }

__device__ __forceinline__ float selu_core(float x) {
    float e = fmaf(__expf(x), SELU_ALPHA, -SELU_ALPHA);
    return x > 0.0f ? x : e;
}

__device__ __forceinline__ bf16x4 cvt4(float4 f) {
    bf16x4 o;
    o.x = (__bf16)f.x; o.y = (__bf16)f.y; o.z = (__bf16)f.z; o.w = (__bf16)f.w;
    return o;
}

// ---------------- slim prep: W1/W2 -> bf16, dj gather (f32), zero out ----------
// float4-granular: [0,NW) W1, [NW,2NW) W2, [2NW, 2NW+ND) dj copy
__global__ __launch_bounds__(256) void prep_k(
        const float* __restrict__ w1, const float* __restrict__ w2,
        const float* __restrict__ dec, const int* __restrict__ Yi,
        __bf16* __restrict__ w1b, __bf16* __restrict__ w2b,
        float* __restrict__ djf, float* __restrict__ out) {
    const int NW = H_ * H_ / 4;                // 147456
    int i = blockIdx.x * 256 + threadIdx.x;
    if (i == 0) out[0] = 0.0f;
    if (i < NW) {
        ((bf16x4*)w1b)[i] = cvt4(((const float4*)w1)[i]);
    } else if (i < 2 * NW) {
        int j = i - NW;
        ((bf16x4*)w2b)[j] = cvt4(((const float4*)w2)[j]);
    } else {
        int j = i - 2 * NW;                    // < 256*192
        int bt = j / 192, c = j % 192;
        int b = bt >> 4;
        int y = Yi[bt];
        ((float4*)djf)[bt * 192 + c] = ((const float4*)dec)[(b * L_ + y) * 192 + c];
    }
}

// ---------------- NT GEMM (WE + WD): C[m][n] = sum_k A[m][k]*B[n][k] ------------
// A is f32 (converted during staging), B is bf16 (global_load_lds DMA).
// BM=64, BN=128, BK=64. 4 waves of 32x64 (2x4 MFMA 16x16x32), 24 barriers total.
// 8-slot XOR swizzle: LDS slot v of row r holds global k-segment v^(r&7)
// (segments = 8 bf16 = 16B). All LDS reads/writes land 8 lanes per 4-bank group.
__device__ __forceinline__ void load16_lds(const __bf16* g, __bf16* l) {
    __builtin_amdgcn_global_load_lds(
        (const __attribute__((address_space(1))) unsigned int*)g,
        (__attribute__((address_space(3))) unsigned int*)l, 16, 0, 0);
}

__global__ __launch_bounds__(256) void gemm_k(
        const float* __restrict__ hn, const float* __restrict__ djf,
        const __bf16* __restrict__ w1b, const __bf16* __restrict__ w2b,
        __bf16* __restrict__ web, __bf16* __restrict__ wdb) {
    __shared__ __bf16 As[64 * 64];    // 8 KB
    __shared__ __bf16 Bs[128 * 64];   // 16 KB

    int bx = blockIdx.x;
    const float* Af; const __bf16* Bw; __bf16* C;
    if (bx < 768) { Af = hn; Bw = w1b; C = web; }
    else          { bx -= 768; Af = djf; Bw = w2b; C = wdb; }
    const int m0 = (bx / 6) * 64, n0 = (bx % 6) * 128;

    const int wave = threadIdx.x >> 6;
    const int lane = threadIdx.x & 63;
    const int wm = (wave >> 1) * 32, wn = (wave & 1) * 64;
    const int lr = lane & 15, q = lane >> 4;

    // ---- A staging map: thread t -> row ar=t>>2, sub asp=t&3 covers global
    //      f32 cols [asp*16, asp*16+16) = segments g0=asp*2, g1=asp*2+1
    const int ar = threadIdx.x >> 2, asp = threadIdx.x & 3;
    const int s0 = (asp * 2)     ^ (ar & 7);
    const int s1 = (asp * 2 + 1) ^ (ar & 7);
    const float* Ag = Af + (size_t)(m0 + ar) * 768 + asp * 16;
    __bf16* Aw0 = &As[ar * 64 + s0 * 8];
    __bf16* Aw1 = &As[ar * 64 + s1 * 8];

    // ---- B DMA map: call c, lane l -> row c*32 + wave*8 + (l>>3), slot l&7,
    //      global segment (l&7)^(l>>3)  (row&7 == l>>3)
    const int brow = wave * 8 + (lane >> 3);
    const int bcol = ((lane & 7) ^ (lane >> 3)) * 8;
    const __bf16* Bg = Bw + (size_t)(n0 + brow) * 768 + bcol;
    __bf16* Bl = &Bs[(wave * 8) * 64];

    // ---- fragment offsets: logical seg s = kc*4+q, slot = s^(lr&7)
    int sl[2];
    sl[0] = ((q)     ^ (lr & 7)) * 8;
    sl[1] = ((4 + q) ^ (lr & 7)) * 8;
    int arow_off[2], brow_off[4];
#pragma unroll
    for (int i = 0; i < 2; ++i) arow_off[i] = (wm + i * 16 + lr) * 64;
#pragma unroll
    for (int j = 0; j < 4; ++j) brow_off[j] = (wn + j * 16 + lr) * 64;

    f32x4 acc[2][4] = {};

    for (int k0 = 0; k0 < 768; k0 += 64) {
        // B: 4 DMA calls x 4 waves x 1KB = 16 KB
#pragma unroll
        for (int c = 0; c < 4; ++c)
            load16_lds(Bg + (size_t)c * 32 * 768 + k0, Bl + c * 32 * 64);
        // A: 64B f32 per thread -> 2 swizzled bf16x8 LDS writes
        float4 a0 = *(const float4*)(Ag + k0);
        float4 a1 = *(const float4*)(Ag + k0 + 4);
        float4 a2 = *(const float4*)(Ag + k0 + 8);
        float4 a3 = *(const float4*)(Ag + k0 + 12);
        bf16x8 p0, p1;
        p0[0]=(__bf16)a0.x; p0[1]=(__bf16)a0.y; p0[2]=(__bf16)a0.z; p0[3]=(__bf16)a0.w;
        p0[4]=(__bf16)a1.x; p0[5]=(__bf16)a1.y; p0[6]=(__bf16)a1.z; p0[7]=(__bf16)a1.w;
        p1[0]=(__bf16)a2.x; p1[1]=(__bf16)a2.y; p1[2]=(__bf16)a2.z; p1[3]=(__bf16)a2.w;
        p1[4]=(__bf16)a3.x; p1[5]=(__bf16)a3.y; p1[6]=(__bf16)a3.z; p1[7]=(__bf16)a3.w;
        *(bf16x8*)Aw0 = p0;
        *(bf16x8*)Aw1 = p1;
        __syncthreads();

#pragma unroll
        for (int kc = 0; kc < 2; ++kc) {
            bf16x8 af[2], bfr[4];
#pragma unroll
            for (int i = 0; i < 2; ++i) af[i]  = *(const bf16x8*)&As[arow_off[i] + sl[kc]];
#pragma unroll
            for (int j = 0; j < 4; ++j) bfr[j] = *(const bf16x8*)&Bs[brow_off[j] + sl[kc]];
#pragma unroll
            for (int i = 0; i < 2; ++i)
#pragma unroll
                for (int j = 0; j < 4; ++j)
                    acc[i][j] = __builtin_amdgcn_mfma_f32_16x16x32_bf16(af[i], bfr[j], acc[i][j], 0, 0, 0);
        }
        __syncthreads();
    }

#pragma unroll
    for (int i = 0; i < 2; ++i)
#pragma unroll
        for (int j = 0; j < 4; ++j)
#pragma unroll
            for (int r = 0; r < 4; ++r) {
                int row = m0 + wm + i * 16 + q * 4 + r;
                int col = n0 + wn + j * 16 + lr;
                C[(size_t)row * 768 + col] = (__bf16)acc[i][j][r];
            }
}

// ---------------- fused scores: per-lane (t,l), no shuffles ----------------
__global__ __launch_bounds__(256) void scores_k(
        const __bf16* __restrict__ web, const __bf16* __restrict__ wdb,
        const float* __restrict__ V, const int* __restrict__ Xi,
        float* __restrict__ scores) {
    __shared__ float    we_s[16][772];
    __shared__ unsigned wd_s[16][388];
    __shared__ float    v_s[768];

    const int b = blockIdx.x, l0 = blockIdx.y * 16;

    for (int c = threadIdx.x; c < 16 * 96; c += 256) {
        int r = c / 96, cc = c % 96;
        uint4 v = *(const uint4*)(web + ((size_t)(b * L_ + l0 + r)) * H_ + cc * 8);
        float4 f0, f1;
        f0.x = bf_lo(v.x); f0.y = bf_hi(v.x); f0.z = bf_lo(v.y); f0.w = bf_hi(v.y);
        f1.x = bf_lo(v.z); f1.y = bf_hi(v.z); f1.z = bf_lo(v.w); f1.w = bf_hi(v.w);
        *(float4*)&we_s[r][cc * 8]     = f0;
        *(float4*)&we_s[r][cc * 8 + 4] = f1;
    }
    for (int c = threadIdx.x; c < 16 * 96; c += 256) {
        int r = c / 96, cc = c % 96;
        *(uint4*)&wd_s[r][cc * 4] = *(const uint4*)(wdb + ((size_t)(b * T_ + r)) * H_ + cc * 8);
    }
    if (threadIdx.x < 192) *(float4*)&v_s[threadIdx.x * 4] = ((const float4*)V)[threadIdx.x];
    __syncthreads();

    const int t = threadIdx.x >> 4;
    const int ls = threadIdx.x & 15;
    const int l = l0 + ls;
    const int X = Xi[b * T_ + t];
    if (!__any(l >= X)) return;

    float a0 = 0.f, a1 = 0.f, a2 = 0.f, a3 = 0.f;
#pragma unroll 4
    for (int h = 0; h < H_; h += 8) {
        float4 w0 = *(const float4*)&we_s[ls][h];
        float4 w1 = *(const float4*)&we_s[ls][h + 4];
        uint4  wd = *(const uint4*)&wd_s[t][h >> 1];
        float4 v0 = *(const float4*)&v_s[h];
        float4 v1 = *(const float4*)&v_s[h + 4];
        a0 = fmaf(selu_core(w0.x + bf_lo(wd.x)), v0.x, a0);
        a1 = fmaf(selu_core(w0.y + bf_hi(wd.x)), v0.y, a1);
        a2 = fmaf(selu_core(w0.z + bf_lo(wd.y)), v0.z, a2);
        a3 = fmaf(selu_core(w0.w + bf_hi(wd.y)), v0.w, a3);
        a0 = fmaf(selu_core(w1.x + bf_lo(wd.z)), v1.x, a0);
        a1 = fmaf(selu_core(w1.y + bf_hi(wd.z)), v1.y, a1);
        a2 = fmaf(selu_core(w1.z + bf_lo(wd.w)), v1.z, a2);
        a3 = fmaf(selu_core(w1.w + bf_hi(wd.w)), v1.w, a3);
    }
    float dot = SELU_SCALE * ((a0 + a1) + (a2 + a3));
    float sc  = dot > 0.0f ? SELU_SCALE * dot
                           : SELU_SCALE * SELU_ALPHA * (__expf(dot) - 1.0f);
    scores[((size_t)(b * T_ + t)) * L_ + l] = sc;
}

// ---------------- per-(b,t) masked logsumexp + gold + mean (atomic) -------------
__global__ __launch_bounds__(64) void loss_k(
        const float* __restrict__ scores, const int* __restrict__ Xi,
        const int* __restrict__ Yi, float* __restrict__ out) {
    const int bt = blockIdx.x;
    const int lane = threadIdx.x;
    const int X = Xi[bt];
    const int Y = Yi[bt];
    const float* row = scores + (size_t)bt * L_;

    float m = -INFINITY;
    for (int l = X + lane; l < L_; l += 64) m = fmaxf(m, row[l]);
#pragma unroll
    for (int off = 32; off > 0; off >>= 1) m = fmaxf(m, __shfl_xor(m, off));

    float s = 0.0f;
    for (int l = X + lane; l < L_; l += 64) s += __expf(row[l] - m);
#pragma unroll
    for (int off = 32; off > 0; off >>= 1) s += __shfl_xor(s, off);

    if (lane == 0)
        atomicAdd(out, (m + __logf(s) - row[Y]) * (1.0f / (B_ * T_)));
}

// ---------------- launch ----------------
extern "C" void kernel_launch(void* const* d_in, const int* in_sizes, int n_in,
                              void* d_out, int out_size, void* d_ws, size_t ws_size,
                              hipStream_t stream) {
    const float* hn  = (const float*)d_in[0];
    const float* dec = (const float*)d_in[1];
    const float* W1  = (const float*)d_in[2];
    const float* W2  = (const float*)d_in[3];
    const float* V   = (const float*)d_in[4];
    const int*   Xi  = (const int*)d_in[5];
    const int*   Yi  = (const int*)d_in[6];
    float* out = (float*)d_out;

    char* ws = (char*)d_ws;
    size_t off = 0;
    auto alloc = [&](size_t bytes) -> char* {
        char* p = ws + off;
        off += (bytes + 255) & ~(size_t)255;
        return p;
    };
    __bf16* w1b    = (__bf16*)alloc((size_t)H_ * H_ * 2);
    __bf16* w2b    = (__bf16*)alloc((size_t)H_ * H_ * 2);
    float*  djf    = (float*)alloc((size_t)B_ * T_ * H_ * 4);
    __bf16* web    = (__bf16*)alloc((size_t)B_ * L_ * H_ * 2);
    __bf16* wdb    = (__bf16*)alloc((size_t)B_ * T_ * H_ * 2);
    float*  scores = (float*)alloc((size_t)B_ * T_ * L_ * 4);

    // prep: (2*147456 + 49152) / 256 = 1344 blocks
    prep_k<<<1344, 256, 0, stream>>>(W1, W2, dec, Yi, w1b, w2b, djf, out);

    // WE (768 blocks) + WD (24 blocks)
    gemm_k<<<792, 256, 0, stream>>>(hn, djf, w1b, w2b, web, wdb);

    scores_k<<<dim3(B_, L_ / 16), 256, 0, stream>>>(web, wdb, V, Xi, scores);
    loss_k<<<B_ * T_, 64, 0, stream>>>(scores, Xi, Yi, out);
}